// Round 5
// baseline (185.273 us; speedup 1.0000x reference)
//
#include <hip/hip_runtime.h>
#include <hip/hip_bf16.h>

typedef __attribute__((ext_vector_type(8))) short short8;
typedef __attribute__((ext_vector_type(8))) unsigned short ushort8;
typedef __attribute__((ext_vector_type(4))) float f32x4;

#define LIN  8192
#define L3V  8189
#define NOUT 128
#define KP   8192
#define BM   32
#define BK   128
#define NT   (KP / BK)       // 64 chunks
#define PITCH (BK + 8)       // 136 shorts/row -> rows advance 4 banks (~2-way, free)

// round-to-nearest-even fp32 -> bf16 (values are finite here)
static __device__ __forceinline__ unsigned short f2bf(float f) {
    union { float f; unsigned u; } c; c.f = f;
    unsigned r = c.u + 0x7FFFu + ((c.u >> 16) & 1u);
    return (unsigned short)(r >> 16);
}

// W [128][8189] fp32 -> Wb in MFMA-fragment-major order, bf16, zero-padded.
// granule g16 = one 16x32 subtile = 64 lanes x 8 bf16; lane l holds
// row (l&15), k-sub (l>>4)*8. Order: chunk t (64) -> col-group g (8) ->
// k-slice s (4) -> lane (64).  Total 131072 granules = 2 MiB.
__global__ void wprep(const float* __restrict__ W, unsigned short* __restrict__ Wb) {
    int idx = blockIdx.x * 256 + threadIdx.x;     // granule index, 0..131071
    const int lane = idx & 63;
    const int s    = (idx >> 6) & 3;
    const int g    = (idx >> 8) & 7;
    const int t    = idx >> 11;
    const int row  = g * 16 + (lane & 15);
    const int k0   = t * BK + s * 32 + (lane >> 4) * 8;
    ushort8 v;
    #pragma unroll
    for (int j = 0; j < 8; ++j) {
        const int k = k0 + j;
        v[j] = (k < L3V) ? f2bf(W[(size_t)row * L3V + k]) : (unsigned short)0;
    }
    *reinterpret_cast<ushort8*>(Wb + (size_t)idx * 8) = v;
}

__global__ __launch_bounds__(512, 4) void fused(
    const float* __restrict__ x,
    const float* __restrict__ w1, const float* __restrict__ b1,
    const float* __restrict__ w2, const float* __restrict__ b2,
    const float* __restrict__ w3, const float* __restrict__ b3,
    const unsigned short* __restrict__ Wb,
    const float* __restrict__ bias,
    float* __restrict__ out)
{
    __shared__ unsigned short hA[2][BM * PITCH];      // 2 x 8704 B = 17408 B total

    const int tid  = threadIdx.x;
    const int row0 = blockIdx.x * BM;

    const float w10 = w1[0], w11 = w1[1], cb1 = b1[0];
    const float w20 = w2[0], w21 = w2[1], cb2 = b2[0];
    const float w30 = w3[0], w31 = w3[1], cb3 = b3[0];

    // staging mapping: 32 rows x 16 segments of 8 h-values
    const int srow = tid >> 4;          // 0..31
    const int scol = (tid & 15) * 8;    // 0,8,...,120
    const float* xrow = x + (size_t)(row0 + srow) * LIN;

    // mfma mapping: 8 waves = 2 row-groups x 4 col-groups; wave = 16 rows x 32 cols
    const int lane = tid & 63;
    const int wid  = tid >> 6;
    const int wr   = wid >> 2;          // 0..1
    const int wc   = wid & 3;           // 0..3
    const int l15  = lane & 15;
    const int koff = (lane >> 4) * 8;
    const int arow_off = (wr * 16 + l15) * PITCH + koff;

    // per-lane W fragment base: chunk t, col-group g = wc*2 + f, slice s, lane
    // shorts offset = ((t*8 + g)*4 + s)*512 + lane*8
    const unsigned short* wbase = Wb + ((size_t)(wc * 2) * 2048 + (size_t)lane * 8);

    f32x4 acc[2];
    acc[0] = (f32x4){0.f, 0.f, 0.f, 0.f};
    acc[1] = (f32x4){0.f, 0.f, 0.f, 0.f};

    // register staging (R2 schedule: store(t+1) then load(t+2))
    float xv[12];

    auto stage_load = [&](int t) {
        const int gk = t * BK + scol;
        if (gk + 12 <= LIN) {                 // false only for t==NT-1 && scol==120
            #pragma unroll
            for (int q = 0; q < 3; ++q) {
                const float4 v = *reinterpret_cast<const float4*>(xrow + gk + q * 4);
                xv[q*4+0] = v.x; xv[q*4+1] = v.y; xv[q*4+2] = v.z; xv[q*4+3] = v.w;
            }
        } else {
            #pragma unroll
            for (int q = 0; q < 2; ++q) {     // gk+8 == LIN here, in bounds
                const float4 v = *reinterpret_cast<const float4*>(xrow + gk + q * 4);
                xv[q*4+0] = v.x; xv[q*4+1] = v.y; xv[q*4+2] = v.z; xv[q*4+3] = v.w;
            }
            xv[8] = 0.f; xv[9] = 0.f; xv[10] = 0.f; xv[11] = 0.f;
            // affected h3 indices are >= L3V and get zero-masked in stage_store
        }
    };

    auto stage_store = [&](int t, int s) {
        const int gk = t * BK + scol;
        float h1[10];
        #pragma unroll
        for (int j = 0; j < 10; ++j)
            h1[j] = fmaxf(fmaf(w10, xv[j], fmaf(w11, xv[j+1], cb1)), 0.0f);
        float h2[9];
        #pragma unroll
        for (int j = 0; j < 9; ++j)
            h2[j] = fmaxf(fmaf(w20, h1[j], fmaf(w21, h1[j+1], cb2)), 0.0f);
        ushort8 hp;
        #pragma unroll
        for (int j = 0; j < 8; ++j) {
            float h3 = fmaxf(fmaf(w30, h2[j], fmaf(w31, h2[j+1], cb3)), 0.0f);
            hp[j] = (gk + j < L3V) ? f2bf(h3) : (unsigned short)0;
        }
        *reinterpret_cast<ushort8*>(&hA[s][srow * PITCH + scol]) = hp;
    };

    auto mfma_tile = [&](int s, int t) {
        const unsigned short* hB = hA[s];
        const unsigned short* wt = wbase + (size_t)t * 16384;   // t*2048 granules * 8
        #pragma unroll
        for (int ks = 0; ks < 4; ++ks) {
            const short8 af = *reinterpret_cast<const short8*>(&hB[arow_off + ks * 32]);
            #pragma unroll
            for (int f = 0; f < 2; ++f) {
                // col-group g = wc*2+f, slice ks: shorts offset f*8192 + ks*512... 
                // g granule stride = 4*64 = 256 granules = 2048 shorts; f adds 2048 shorts
                const short8 bf = *reinterpret_cast<const short8*>(wt + f * 2048 + ks * 512);
                acc[f] = __builtin_amdgcn_mfma_f32_16x16x32_bf16(af, bf, acc[f], 0, 0, 0);
            }
        }
    };

    // prologue: fill buf0, start loads for chunk 1
    stage_load(0);
    stage_store(0, 0);
    stage_load(1);
    __syncthreads();

    int sel = 0;
    #pragma unroll 1
    for (int t = 0; t < NT; ++t) {
        mfma_tile(sel, t);                            // regs for t+1 already in flight
        if (t + 1 < NT) stage_store(t + 1, sel ^ 1);  // consume regs -> LDS
        if (t + 2 < NT) stage_load(t + 2);            // refill regs, stay in flight
        __syncthreads();
        sel ^= 1;
    }

    // epilogue: C[m][n]: col = lane&15, row = (lane>>4)*4 + j   [m89 layout]
    #pragma unroll
    for (int f = 0; f < 2; ++f) {
        const int col = wc * 32 + f * 16 + l15;
        const float bv = bias[col];
        #pragma unroll
        for (int j = 0; j < 4; ++j) {
            const int grow = row0 + wr * 16 + (lane >> 4) * 4 + j;
            out[(size_t)grow * NOUT + col] = acc[f][j] + bv;
        }
    }
}

extern "C" void kernel_launch(void* const* d_in, const int* in_sizes, int n_in,
                              void* d_out, int out_size, void* d_ws, size_t ws_size,
                              hipStream_t stream) {
    const float* x  = (const float*)d_in[0];
    const float* w1 = (const float*)d_in[1];
    const float* b1 = (const float*)d_in[2];
    const float* w2 = (const float*)d_in[3];
    const float* b2 = (const float*)d_in[4];
    const float* w3 = (const float*)d_in[5];
    const float* b3 = (const float*)d_in[6];
    const float* W  = (const float*)d_in[7];
    const float* b  = (const float*)d_in[8];
    float* out = (float*)d_out;
    unsigned short* Wb = (unsigned short*)d_ws;   // 2 MiB, fragment-major

    wprep<<<dim3(512), dim3(256), 0, stream>>>(W, Wb);
    fused<<<dim3(16384 / BM), dim3(512), 0, stream>>>(
        x, w1, b1, w2, b2, w3, b3, Wb, b, out);
}

// Round 6
// 146.038 us; speedup vs baseline: 1.2687x; 1.2687x over previous
//
#include <hip/hip_runtime.h>
#include <hip/hip_bf16.h>

typedef __attribute__((ext_vector_type(8))) short short8;
typedef __attribute__((ext_vector_type(8))) unsigned short ushort8;
typedef __attribute__((ext_vector_type(4))) float f32x4;

#define LIN  8192
#define L3V  8189
#define NOUT 128
#define KP   8192
#define BM   64
#define BK   64
#define NTH  64              // chunks per K-half (4096 / BK)
#define PITCH (BK + 8)       // 72 shorts/row -> rows advance 4 banks (~2-way, free)
#define NROW 16384

// round-to-nearest-even fp32 -> bf16 (values are finite here)
static __device__ __forceinline__ unsigned short f2bf(float f) {
    union { float f; unsigned u; } c; c.f = f;
    unsigned r = c.u + 0x7FFFu + ((c.u >> 16) & 1u);
    return (unsigned short)(r >> 16);
}

// W [128][8189] fp32 -> Wb [128][8192] bf16, zero-padded tail
__global__ void wprep(const float* __restrict__ W, unsigned short* __restrict__ Wb) {
    int idx = blockIdx.x * 256 + threadIdx.x;     // 0 .. 128*8192-1
    int n = idx >> 13;
    int k = idx & (KP - 1);
    float v = (k < L3V) ? W[(size_t)n * L3V + k] : 0.0f;
    Wb[idx] = f2bf(v);
}

// out = partial[0] + partial[1] + bias   (524288 float4s)
__global__ void reduce_out(const float* __restrict__ p,
                           const float* __restrict__ bias,
                           float* __restrict__ out) {
    const int idx = blockIdx.x * 256 + threadIdx.x;          // float4 index
    const float4 a = reinterpret_cast<const float4*>(p)[idx];
    const float4 c = reinterpret_cast<const float4*>(p)[idx + (NROW * NOUT / 4)];
    const float4 bb = *reinterpret_cast<const float4*>(bias + ((idx * 4) & (NOUT - 1)));
    float4 o;
    o.x = a.x + c.x + bb.x;
    o.y = a.y + c.y + bb.y;
    o.z = a.z + c.z + bb.z;
    o.w = a.w + c.w + bb.w;
    reinterpret_cast<float4*>(out)[idx] = o;
}

__global__ __launch_bounds__(512, 4) void fused(
    const float* __restrict__ x,
    const float* __restrict__ w1, const float* __restrict__ b1,
    const float* __restrict__ w2, const float* __restrict__ b2,
    const float* __restrict__ w3, const float* __restrict__ b3,
    const unsigned short* __restrict__ Wb,
    float* __restrict__ part)                     // [2][NROW][NOUT] fp32
{
    __shared__ unsigned short hA[2][BM * PITCH];      // 2 x  9216 B
    __shared__ unsigned short wA[2][NOUT * PITCH];    // 2 x 18432 B  (55296 B -> 2 blocks/CU)

    const int tid  = threadIdx.x;
    const int row0 = blockIdx.x * BM;
    const int kh   = blockIdx.y;                  // K-half: chunks [kh*NTH, kh*NTH+NTH)
    const int tb   = kh * NTH;

    const float w10 = w1[0], w11 = w1[1], cb1 = b1[0];
    const float w20 = w2[0], w21 = w2[1], cb2 = b2[0];
    const float w30 = w3[0], w31 = w3[1], cb3 = b3[0];

    // staging mapping: 64 rows x 8 segments of 8 h-values
    const int srow = tid >> 3;          // 0..63
    const int scol = (tid & 7) * 8;     // 0,8,...,56
    const float* xrow = x + (size_t)(row0 + srow) * LIN;

    // W staging mapping: 128 rows x 4 quarters of 16 cols
    const int wn = tid >> 2;            // 0..127
    const int wq = tid & 3;             // 0..3
    const unsigned short* wrow = Wb + (size_t)wn * KP + wq * 16;

    // mfma mapping: 8 waves = 4 row-groups x 2 col-groups; wave = 16 rows x 64 cols
    const int lane = tid & 63;
    const int wid  = tid >> 6;
    const int wr   = wid >> 1;          // 0..3
    const int wc   = wid & 1;           // 0..1
    const int l15  = lane & 15;
    const int koff = (lane >> 4) * 8;
    const int arow_off = (wr * 16 + l15) * PITCH + koff;

    f32x4 acc[4];
    #pragma unroll
    for (int f = 0; f < 4; ++f) acc[f] = (f32x4){0.f, 0.f, 0.f, 0.f};

    // single register staging set (R2 schedule; R3's dual-set regressed)
    float   xv[12];
    ushort8 wv[2];

    auto stage_load = [&](int t) {                // t in [0, NTH)
        const int gk = (tb + t) * BK + scol;
        if (gk + 12 <= LIN) {                     // false only at the very tail
            #pragma unroll
            for (int q = 0; q < 3; ++q) {
                const float4 v = *reinterpret_cast<const float4*>(xrow + gk + q * 4);
                xv[q*4+0] = v.x; xv[q*4+1] = v.y; xv[q*4+2] = v.z; xv[q*4+3] = v.w;
            }
        } else {
            #pragma unroll
            for (int q = 0; q < 2; ++q) {         // gk+8 == LIN here, in bounds
                const float4 v = *reinterpret_cast<const float4*>(xrow + gk + q * 4);
                xv[q*4+0] = v.x; xv[q*4+1] = v.y; xv[q*4+2] = v.z; xv[q*4+3] = v.w;
            }
            xv[8] = 0.f; xv[9] = 0.f; xv[10] = 0.f; xv[11] = 0.f;
            // affected h3 indices are >= L3V and get zero-masked in stage_store
        }
        const ushort8* wsrc = reinterpret_cast<const ushort8*>(wrow + (tb + t) * BK);
        wv[0] = wsrc[0];
        wv[1] = wsrc[1];
    };

    auto stage_store = [&](int t, int s) {
        const int gk = (tb + t) * BK + scol;
        float h1[10];
        #pragma unroll
        for (int j = 0; j < 10; ++j)
            h1[j] = fmaxf(fmaf(w10, xv[j], fmaf(w11, xv[j+1], cb1)), 0.0f);
        float h2[9];
        #pragma unroll
        for (int j = 0; j < 9; ++j)
            h2[j] = fmaxf(fmaf(w20, h1[j], fmaf(w21, h1[j+1], cb2)), 0.0f);
        ushort8 hp;
        #pragma unroll
        for (int j = 0; j < 8; ++j) {
            float h3 = fmaxf(fmaf(w30, h2[j], fmaf(w31, h2[j+1], cb3)), 0.0f);
            hp[j] = (gk + j < L3V) ? f2bf(h3) : (unsigned short)0;
        }
        *reinterpret_cast<ushort8*>(&hA[s][srow * PITCH + scol]) = hp;
        ushort8* wdst = reinterpret_cast<ushort8*>(&wA[s][wn * PITCH + wq * 16]);
        wdst[0] = wv[0];
        wdst[1] = wv[1];
    };

    auto mfma_tile = [&](int s) {
        const unsigned short* hB = hA[s];
        const unsigned short* wB = wA[s];
        #pragma unroll
        for (int kk = 0; kk < BK; kk += 32) {
            const short8 af = *reinterpret_cast<const short8*>(&hB[arow_off + kk]);
            #pragma unroll
            for (int f = 0; f < 4; ++f) {
                const int bn = wc * 64 + f * 16 + l15;
                const short8 bf = *reinterpret_cast<const short8*>(&wB[bn * PITCH + kk + koff]);
                acc[f] = __builtin_amdgcn_mfma_f32_16x16x32_bf16(af, bf, acc[f], 0, 0, 0);
            }
        }
    };

    // prologue: fill buf0, start loads for chunk 1
    stage_load(0);
    stage_store(0, 0);
    stage_load(1);
    __syncthreads();

    int sel = 0;
    #pragma unroll 1
    for (int t = 0; t < NTH; ++t) {
        mfma_tile(sel);                                // regs for t+1 already in flight
        if (t + 1 < NTH) stage_store(t + 1, sel ^ 1);  // consume regs -> LDS
        if (t + 2 < NTH) stage_load(t + 2);            // refill regs, stay in flight
        __syncthreads();
        sel ^= 1;
    }

    // epilogue -> partial buffer (no bias; reduce adds it)
    // C[m][n]: col = lane&15, row = (lane>>4)*4 + j   [m89 layout]
    float* pbase = part + (size_t)kh * NROW * NOUT;
    #pragma unroll
    for (int f = 0; f < 4; ++f) {
        const int col = wc * 64 + f * 16 + l15;
        #pragma unroll
        for (int j = 0; j < 4; ++j) {
            const int grow = row0 + wr * 16 + (lane >> 4) * 4 + j;
            pbase[(size_t)grow * NOUT + col] = acc[f][j];
        }
    }
}

extern "C" void kernel_launch(void* const* d_in, const int* in_sizes, int n_in,
                              void* d_out, int out_size, void* d_ws, size_t ws_size,
                              hipStream_t stream) {
    const float* x  = (const float*)d_in[0];
    const float* w1 = (const float*)d_in[1];
    const float* b1 = (const float*)d_in[2];
    const float* w2 = (const float*)d_in[3];
    const float* b2 = (const float*)d_in[4];
    const float* w3 = (const float*)d_in[5];
    const float* b3 = (const float*)d_in[6];
    const float* W  = (const float*)d_in[7];
    const float* b  = (const float*)d_in[8];
    float* out = (float*)d_out;

    unsigned short* Wb   = (unsigned short*)d_ws;                 // 2 MiB
    float*          part = (float*)((char*)d_ws + (2u << 20));    // 16 MiB partials

    wprep<<<dim3((NOUT * KP) / 256), dim3(256), 0, stream>>>(W, Wb);
    fused<<<dim3(NROW / BM, 2), dim3(512), 0, stream>>>(
        x, w1, b1, w2, b2, w3, b3, Wb, part);
    reduce_out<<<dim3(NROW * NOUT / 4 / 256), dim3(256), 0, stream>>>(part, b, out);
}